// Round 16
// baseline (177.314 us; speedup 1.0000x reference)
//
#include <hip/hip_runtime.h>

#define N_ITEMS 65536

// ---------------- Kernel 1: q = x @ W, FULL-K 64x64 tiles, 512 threads ------
// R15 post-mortem: full-K at 256 threads = 1 wave/SIMD -> latency-bound
// (Occ 9.7%, VALU 28%, 52us). Fix: 512-thread blocks, same 64x64 tile ->
// 8 waves/CU (2/SIMD). Waves 0-3 stage As, 4-7 stage Bs (wave-uniform
// branch); all threads compute a 2x4 micro-tile. Same k-order per output
// -> q bit-identical to R15 (passed, absmax 0.015625).
// z==1 plane: 32 blocks (y<2) pack key_codes -> pcodes/poffs.
__launch_bounds__(512)
__global__ void gemm_q_kernel(const float* __restrict__ A,
                              const float* __restrict__ W,
                              const int* __restrict__ key_codes,
                              float* __restrict__ q,
                              unsigned long long* __restrict__ pcodes,
                              uint4* __restrict__ poffs) {
  if (blockIdx.z == 1) {
    if (blockIdx.y >= 2) return;
    const int g0 = (((int)blockIdx.y * 16 + (int)blockIdx.x) * 512 + (int)threadIdx.x) * 4;
#pragma unroll
    for (int t = 0; t < 4; t++) {
      const int gid = g0 + t;
      unsigned long long p = 0ull;
      unsigned h[8];
#pragma unroll
      for (int j = 0; j < 8; j++) {
        const unsigned c = (unsigned)key_codes[gid * 8 + j] & 255u;
        p |= (unsigned long long)c << (8 * j);
        h[j] = c << 6;
      }
      pcodes[gid] = p;
      poffs[gid] = make_uint4(h[0] | (h[1] << 16), h[2] | (h[3] << 16),
                              h[4] | (h[5] << 16), h[6] | (h[7] << 16));
    }
    return;
  }

  __shared__ float As[16][68];
  __shared__ float Bs[16][68];
  const int tid = threadIdx.x;
  const int tx = tid & 15, ty = tid >> 4;        // ty 0..31
  const int rb = blockIdx.y * 64, cb = blockIdx.x * 64;
  const int ar = (tid & 255) >> 2, ac = (tid & 3) << 2;
  const int bk = (tid & 255) >> 4, bc = (tid & 15) << 2;
  const bool isA = tid < 256;

  float4 vld;
  if (isA) vld = *(const float4*)&A[(rb + ar) * 1024 + ac];
  else     vld = *(const float4*)&W[bk * 1024 + cb + bc];

  float acc[2][4] = {};
  for (int k0 = 0; k0 < 1024; k0 += 16) {
    if (isA) {
      As[ac + 0][ar] = vld.x; As[ac + 1][ar] = vld.y;
      As[ac + 2][ar] = vld.z; As[ac + 3][ar] = vld.w;
    } else {
      *(float4*)&Bs[bk][bc] = vld;
    }
    __syncthreads();
    if (k0 + 16 < 1024) {
      if (isA) vld = *(const float4*)&A[(rb + ar) * 1024 + k0 + 16 + ac];
      else     vld = *(const float4*)&W[(k0 + 16 + bk) * 1024 + cb + bc];
    }
#pragma unroll
    for (int kk = 0; kk < 16; kk++) {
      const float2 a2 = *(const float2*)&As[kk][ty << 1];
      const float4 b4 = *(const float4*)&Bs[kk][tx << 2];
      acc[0][0] = fmaf(a2.x, b4.x, acc[0][0]);
      acc[0][1] = fmaf(a2.x, b4.y, acc[0][1]);
      acc[0][2] = fmaf(a2.x, b4.z, acc[0][2]);
      acc[0][3] = fmaf(a2.x, b4.w, acc[0][3]);
      acc[1][0] = fmaf(a2.y, b4.x, acc[1][0]);
      acc[1][1] = fmaf(a2.y, b4.y, acc[1][1]);
      acc[1][2] = fmaf(a2.y, b4.z, acc[1][2]);
      acc[1][3] = fmaf(a2.y, b4.w, acc[1][3]);
    }
    __syncthreads();
  }
#pragma unroll
  for (int r = 0; r < 2; r++) {
    const int row = rb + (ty << 1) + r;
    *(float4*)&q[row * 1024 + cb + (tx << 2)] =
        make_float4(acc[r][0], acc[r][1], acc[r][2], acc[r][3]);
  }
}

// ---------------- Kernel 2: lut + DIRECT i8 table emission ------------------
// i8 value = clamp(rint(dt - qa[r] - 96), -127, 127) + 128 -- per-row offset
// preserves per-row ranking exactly; clips covered by lim_add=20 budget.
__launch_bounds__(256)
__global__ void lut_kernel(const float* __restrict__ q,
                           const float* __restrict__ kcb,
                           float* __restrict__ lut,
                           unsigned* __restrict__ i8lut) {
  __shared__ float As[32][68];
  __shared__ float Bs[32][68];
  const int tid = threadIdx.x;
  const int tx = tid & 15, ty = tid >> 4;
  const int m = blockIdx.z;
  const int rb = blockIdx.y * 64;
  const int cb0 = blockIdx.x * 64;
  float acc[4][4] = {};
  float qa[4] = {}, cs[4] = {};
  for (int k0 = 0; k0 < 128; k0 += 32) {
#pragma unroll
    for (int l = 0; l < 2; l++) {
      const int e = tid + l * 256;
      const int row = e >> 3, c4 = (e & 7) << 2;
      const float4 va = *(const float4*)&q[(rb + row) * 1024 + m * 128 + k0 + c4];
      As[c4 + 0][row] = va.x; As[c4 + 1][row] = va.y;
      As[c4 + 2][row] = va.z; As[c4 + 3][row] = va.w;
      const float4 vb = *(const float4*)&kcb[(m * 256 + cb0 + row) * 128 + k0 + c4];
      Bs[c4 + 0][row] = vb.x; Bs[c4 + 1][row] = vb.y;
      Bs[c4 + 2][row] = vb.z; Bs[c4 + 3][row] = vb.w;
    }
    __syncthreads();
#pragma unroll
    for (int kk = 0; kk < 32; kk++) {
      const float4 a = *(const float4*)&As[kk][ty << 2];
      const float4 b = *(const float4*)&Bs[kk][tx << 2];
      const float ar[4] = {a.x, a.y, a.z, a.w};
      const float br[4] = {b.x, b.y, b.z, b.w};
#pragma unroll
      for (int r = 0; r < 4; r++)
#pragma unroll
        for (int c = 0; c < 4; c++)
          acc[r][c] = fmaf(ar[r], br[c], acc[r][c]);
#pragma unroll
      for (int r = 0; r < 4; r++) qa[r] = fmaf(ar[r], ar[r], qa[r]);
#pragma unroll
      for (int c = 0; c < 4; c++) cs[c] = fmaf(br[c], br[c], cs[c]);
    }
    __syncthreads();
  }
  unsigned wpk[4] = {0u, 0u, 0u, 0u};
#pragma unroll
  for (int r = 0; r < 4; r++) {
    const int row = rb + (ty << 2) + r;
    const int col = cb0 + (tx << 2);
    float4 v;
    v.x = qa[r] + cs[0] - 2.0f * acc[r][0];
    v.y = qa[r] + cs[1] - 2.0f * acc[r][1];
    v.z = qa[r] + cs[2] - 2.0f * acc[r][2];
    v.w = qa[r] + cs[3] - 2.0f * acc[r][3];
    *(float4*)&lut[row * 2048 + m * 256 + col] = v;
    const float vb4[4] = {v.x, v.y, v.z, v.w};
#pragma unroll
    for (int c = 0; c < 4; c++) {
      int iv = (int)rintf(vb4[c] - qa[r] - 96.0f);
      iv = max(-127, min(127, iv));
      wpk[c] |= (unsigned)(iv + 128) << (8 * r);
    }
  }
  const int gq = (rb >> 2) + ty;
  const int e0 = m * 256 + cb0 + (tx << 2);
  *(uint4*)&i8lut[gq * 2048 + e0] = make_uint4(wpk[0], wpk[1], wpk[2], wpk[3]);
}

// ---------------- Kernel 3a: FUSED scan+select (R11 best-known config) ------
extern __shared__ char dyn_lds[];

__launch_bounds__(1024)
__global__ void scansel_kernel(const float* __restrict__ lutf,
                               const unsigned* __restrict__ i8lut,
                               const uint4* __restrict__ poffs,
                               const unsigned long long* __restrict__ pcodes,
                               const int* __restrict__ value_codes,
                               const float* __restrict__ vcb,
                               const float* __restrict__ bias,
                               float* __restrict__ out) {
  char* repb = dyn_lds;                               // 131072 B table
  const int tid = threadIdx.x;
  const int g = blockIdx.x;

  // ---- replicate: entry e -> 16 consecutive dwords (e*16+r) ----
  {
    const int lane = tid & 63;
    const uint2 tv = *(const uint2*)&i8lut[g * 2048 + tid * 2];
    const uint4 q0 = make_uint4(tv.x, tv.x, tv.x, tv.x);
    const uint4 q1 = make_uint4(tv.y, tv.y, tv.y, tv.y);
    uint4* repv = (uint4*)dyn_lds;
#pragma unroll
    for (int k = 0; k < 4; k++) {
      const int kk = (k + lane) & 3;
      repv[tid * 8 + kk] = q0;
      repv[tid * 8 + 4 + kk] = q1;
    }
  }
  __syncthreads();

  // ---- scan: 64 items/lane, ping-pong-buffered 8 dword lookups/item ----
  const int r = tid & 15;
  const char* base0 = repb + (r << 2);            // segments 0..3 via imm offs
  const char* base1 = repb + 65536 + (r << 2);    // segments 4..7
  unsigned k0[4], k1[4];
#pragma unroll
  for (int j = 0; j < 4; j++) { k0[j] = 0xFFFFFFFFu; k1[j] = 0xFFFFFFFFu; }

  unsigned A[8], B[8];

  auto issue = [&](unsigned (&BUF)[8], const uint4 cw) {
    BUF[0] = *(const unsigned*)(base0 + (cw.x & 0xFFFFu));
    BUF[1] = *(const unsigned*)(base0 + (cw.x >> 16) + 16384);
    BUF[2] = *(const unsigned*)(base0 + (cw.y & 0xFFFFu) + 32768);
    BUF[3] = *(const unsigned*)(base0 + (cw.y >> 16) + 49152);
    BUF[4] = *(const unsigned*)(base1 + (cw.z & 0xFFFFu));
    BUF[5] = *(const unsigned*)(base1 + (cw.z >> 16) + 16384);
    BUF[6] = *(const unsigned*)(base1 + (cw.w & 0xFFFFu) + 32768);
    BUF[7] = *(const unsigned*)(base1 + (cw.w >> 16) + 49152);
  };

  auto consume = [&](const unsigned (&BUF)[8], const int it) {
    const unsigned M = 0x00FF00FFu;
    unsigned accA = BUF[0] & M;
    unsigned accB = (BUF[0] >> 8) & M;
#pragma unroll
    for (int j = 1; j < 8; j++) {
      accA += BUF[j] & M;
      accB += (BUF[j] >> 8) & M;
    }
    const int ss[4] = {(int)(accA & 0xFFFFu), (int)(accB & 0xFFFFu),
                       (int)(accA >> 16), (int)(accB >> 16)};
#pragma unroll
    for (int j = 0; j < 4; j++) {
      const unsigned key = ((unsigned)ss[j] << 6) | (unsigned)it;
      const unsigned mx = (k0[j] > key) ? k0[j] : key;
      k0[j] = (k0[j] < key) ? k0[j] : key;
      k1[j] = (k1[j] < mx) ? k1[j] : mx;
    }
  };

  issue(A, poffs[tid]);                 // item 0
  uint4 cJ1 = poffs[tid + 1024];        // codes for item it+1
  uint4 cJ2 = poffs[tid + 2048];        // codes for item it+2

  for (int it = 0; it < 64; it += 2) {
    const uint4 cN1 = poffs[tid + (((it + 3) & 63) << 10)];
    const uint4 cN2 = poffs[tid + (((it + 4) & 63) << 10)];
    issue(B, cJ1);
    consume(A, it);
    issue(A, cJ2);
    consume(B, it + 1);
    cJ1 = cN1; cJ2 = cN2;
  }

  // ================= SELECT PHASE (table is dead; overlay LDS) =============
  __syncthreads();   // all table reads complete before overlay writes

  unsigned* cl  = (unsigned*)dyn_lds;                       // [4][256] (d<<16)|n
  float* wts    = (float*)(dyn_lds + 4096);                 // [4][256]
  unsigned long long* sv8 = (unsigned long long*)(dyn_lds + 8192); // [4][256]
  float* gred   = (float*)(dyn_lds + 16384);                // [4][4] scratch
  unsigned* rmin = (unsigned*)(dyn_lds + 16448);            // [4]
  int* rcnt     = (int*)(dyn_lds + 16464);                  // [4]
  float* rws    = (float*)(dyn_lds + 16480);                // [4] 1/wsum

  if (tid < 4) { rmin[tid] = 0xFFFFFFFFu; rcnt[tid] = 0; }
  __syncthreads();

  // per-row quantized min
#pragma unroll
  for (int j = 0; j < 4; j++) {
    unsigned d = k0[j] >> 6;
#pragma unroll
    for (int off = 32; off > 0; off >>= 1) {
      const unsigned o = __shfl_xor(d, off);
      d = (o < d) ? o : d;
    }
    if ((tid & 63) == 0) atomicMin(&rmin[j], d);
  }
  __syncthreads();

  // ballot-compact candidates within window
  {
    const int lane = tid & 63;
    const unsigned long long lm = (1ull << lane) - 1ull;
#pragma unroll
    for (int j = 0; j < 4; j++) {
      const unsigned lim = rmin[j] + 20u;
#pragma unroll
      for (int c = 0; c < 2; c++) {
        const unsigned key = c ? k1[j] : k0[j];
        const unsigned d = key >> 6;
        const bool pred = d <= lim;
        const unsigned long long m = __ballot(pred);
        int base = 0;
        if (lane == 0 && m) base = atomicAdd(&rcnt[j], __popcll(m));
        base = __shfl(base, 0);
        if (pred) {
          const int pos = base + __popcll(m & lm);
          if (pos < 256)
            cl[j * 256 + pos] = (d << 16) | ((key & 63u) << 10) | (unsigned)tid;
        }
      }
    }
  }
  __syncthreads();

  // exact fp32 re-score (group j = tid>>8 handles row j)
  const int gj = tid >> 8, gt = tid & 255;
  const int cnt_g = min(rcnt[gj], 256);
  float dex = 1e30f;
  if (gt < cnt_g) {
    const unsigned pc = cl[gj * 256 + gt];
    const int n = (int)(pc & 0xFFFFu);
    const unsigned long long c8 = pcodes[n];
    const uint4 vc0 = *(const uint4*)&value_codes[n * 8];
    const uint4 vc1 = *(const uint4*)&value_codes[n * 8 + 4];
    sv8[gj * 256 + gt] =
        (unsigned long long)(vc0.x & 255u)        | ((unsigned long long)(vc0.y & 255u) << 8)  |
        ((unsigned long long)(vc0.z & 255u) << 16) | ((unsigned long long)(vc0.w & 255u) << 24) |
        ((unsigned long long)(vc1.x & 255u) << 32) | ((unsigned long long)(vc1.y & 255u) << 40) |
        ((unsigned long long)(vc1.z & 255u) << 48) | ((unsigned long long)(vc1.w & 255u) << 56);
    const float* lrow = lutf + ((g << 2) + gj) * 2048;
    const unsigned lo = (unsigned)c8, hi = (unsigned)(c8 >> 32);
    dex  = lrow[        (lo       & 255u)];
    dex += lrow[ 256 + ((lo >>  8) & 255u)];
    dex += lrow[ 512 + ((lo >> 16) & 255u)];
    dex += lrow[ 768 + ((lo >> 24)       )];
    dex += lrow[1024 + ( hi        & 255u)];
    dex += lrow[1280 + ((hi >>  8) & 255u)];
    dex += lrow[1536 + ((hi >> 16) & 255u)];
    dex += lrow[1792 + ((hi >> 24)       )];
  }
  // group min of dex (4 waves per group)
  float mnf = dex;
#pragma unroll
  for (int off = 32; off > 0; off >>= 1) mnf = fminf(mnf, __shfl_xor(mnf, off));
  if ((tid & 63) == 0) gred[gj * 4 + ((tid >> 6) & 3)] = mnf;
  __syncthreads();
  const float dminx = fminf(fminf(gred[gj * 4], gred[gj * 4 + 1]),
                            fminf(gred[gj * 4 + 2], gred[gj * 4 + 3]));
  const float w = (gt < cnt_g) ? __expf(dminx - dex) : 0.f;
  wts[gj * 256 + gt] = w;
  // group sum of w
  float sw_ = w;
#pragma unroll
  for (int off = 32; off > 0; off >>= 1) sw_ += __shfl_xor(sw_, off);
  __syncthreads();   // gred min-reads done; safe to overwrite
  if ((tid & 63) == 0) gred[gj * 4 + ((tid >> 6) & 3)] = sw_;
  __syncthreads();
  if (gt == 0)
    rws[gj] = 1.0f / (gred[gj * 4] + gred[gj * 4 + 1] + gred[gj * 4 + 2] + gred[gj * 4 + 3]);
  __syncthreads();

  // value gather + output: rows in pairs (h = tid>>9 selects row of pair)
  const int h = tid >> 9, u = tid & 511;
  const int col = u << 2;
  const int mv = col >> 8;
  const int co = col & 255;
  const float* vb2 = vcb + mv * 65536 + co;
  const float4 bb = *(const float4*)&bias[col];
#pragma unroll
  for (int jr = 0; jr < 2; jr++) {
    const int j = (jr << 1) | h;
    const int row = (g << 2) + j;
    const int cj = min(rcnt[j], 256);
    float4 acc = make_float4(0.f, 0.f, 0.f, 0.f);
    int k = 0;
    for (; k + 1 < cj; k += 2) {
      const float w0 = wts[j * 256 + k];
      const float w1 = wts[j * 256 + k + 1];
      const unsigned c0 = (unsigned)((sv8[j * 256 + k] >> (mv * 8)) & 255ull);
      const unsigned c1 = (unsigned)((sv8[j * 256 + k + 1] >> (mv * 8)) & 255ull);
      const float4 v0 = *(const float4*)(vb2 + c0 * 256);
      const float4 v1 = *(const float4*)(vb2 + c1 * 256);
      acc.x = fmaf(w0, v0.x, acc.x); acc.y = fmaf(w0, v0.y, acc.y);
      acc.z = fmaf(w0, v0.z, acc.z); acc.w = fmaf(w0, v0.w, acc.w);
      acc.x = fmaf(w1, v1.x, acc.x); acc.y = fmaf(w1, v1.y, acc.y);
      acc.z = fmaf(w1, v1.z, acc.z); acc.w = fmaf(w1, v1.w, acc.w);
    }
    if (k < cj) {
      const float w0 = wts[j * 256 + k];
      const unsigned c0 = (unsigned)((sv8[j * 256 + k] >> (mv * 8)) & 255ull);
      const float4 v0 = *(const float4*)(vb2 + c0 * 256);
      acc.x = fmaf(w0, v0.x, acc.x); acc.y = fmaf(w0, v0.y, acc.y);
      acc.z = fmaf(w0, v0.z, acc.z); acc.w = fmaf(w0, v0.w, acc.w);
    }
    const float iv = rws[j];
    *(float4*)&out[row * 2048 + col] =
        make_float4(fmaf(acc.x, iv, bb.x), fmaf(acc.y, iv, bb.y),
                    fmaf(acc.z, iv, bb.z), fmaf(acc.w, iv, bb.w));
  }
}

// ---------------- Kernel 3b: fallback 64KB scan (verified) ----------------
__launch_bounds__(512)
__global__ void scan16_kernel(const float* __restrict__ lut,
                              const unsigned long long* __restrict__ pcodes,
                              unsigned* __restrict__ cand_d,
                              unsigned short* __restrict__ cand_n) {
  __shared__ short sRep[32768];
  const int tid = threadIdx.x;
  const int b = blockIdx.x;

  const float4 v4 = *(const float4*)&lut[b * 2048 + tid * 4];
  float s4 = v4.x + v4.y + v4.z + v4.w;
#pragma unroll
  for (int off = 32; off > 0; off >>= 1) s4 += __shfl_xor(s4, off);
  const float mean = s4 * (1.0f / 256.0f);

  const float vals[4] = {v4.x, v4.y, v4.z, v4.w};
#pragma unroll
  for (int k2 = 0; k2 < 4; k2++) {
    float f = (vals[k2] - mean) * 64.0f;
    f = fmaxf(fminf(f, 32000.0f), -32000.0f);
    const int iv = (int)rintf(f);
    const unsigned hw = (unsigned)(unsigned short)iv;
    const unsigned wrd = hw | (hw << 16);
    const uint4 wv = make_uint4(wrd, wrd, wrd, wrd);
    const int e = tid * 4 + k2;
    *(uint4*)&((unsigned*)sRep)[e * 8] = wv;
    *(uint4*)&((unsigned*)sRep)[e * 8 + 4] = wv;
  }
  __syncthreads();

  const int r = tid & 15;
  int d0 = 0x7FFFFFFF, d1 = 0x7FFFFFFF, d2 = 0x7FFFFFFF, d3 = 0x7FFFFFFF;
  int i0 = 0, i1 = 0, i2 = 0, i3 = 0;

  unsigned long long c8 = pcodes[tid];
  for (int it = 0; it < 128; it++) {
    const int n = tid + (it << 9);
    unsigned long long nxt = 0ull;
    if (it < 127) nxt = pcodes[n + 512];
    const unsigned lo = (unsigned)c8;
    const unsigned hi = (unsigned)(c8 >> 32);
    int s;
    s  = sRep[(((lo      ) & 255u) << 4) + r        ];
    s += sRep[(((lo >>  8) & 255u) << 4) + r +  4096];
    s += sRep[(((lo >> 16) & 255u) << 4) + r +  8192];
    s += sRep[(((lo >> 24)       ) << 4) + r + 12288];
    s += sRep[(((hi      ) & 255u) << 4) + r + 16384];
    s += sRep[(((hi >>  8) & 255u) << 4) + r + 20480];
    s += sRep[(((hi >> 16) & 255u) << 4) + r + 24576];
    s += sRep[(((hi >> 24)       ) << 4) + r + 28672];
    if (s < d3) {
      if (s < d1) {
        if (s < d0) { d3 = d2; i3 = i2; d2 = d1; i2 = i1; d1 = d0; i1 = i0; d0 = s; i0 = n; }
        else        { d3 = d2; i3 = i2; d2 = d1; i2 = i1; d1 = s; i1 = n; }
      } else {
        if (s < d2) { d3 = d2; i3 = i2; d2 = s; i2 = n; }
        else        { d3 = s; i3 = n; }
      }
    }
    c8 = nxt;
  }

  const int base = b * 2048 + tid * 4;
  const uint4 dv = make_uint4((unsigned)(d0 + 0x40000000), (unsigned)(d1 + 0x40000000),
                              (unsigned)(d2 + 0x40000000), (unsigned)(d3 + 0x40000000));
  *(uint4*)&cand_d[base] = dv;
  const unsigned ni01 = (unsigned)i0 | ((unsigned)i1 << 16);
  const unsigned ni23 = (unsigned)i2 | ((unsigned)i3 << 16);
  *(uint2*)&cand_n[base] = make_uint2(ni01, ni23);
}

// ---------------- Kernel 4 (fallback path only): select + re-score ----------
__launch_bounds__(256)
__global__ void select_kernel(const unsigned* __restrict__ cand_d,
                              const unsigned short* __restrict__ cand_n,
                              const int* __restrict__ value_codes,
                              const float* __restrict__ vcb,
                              const float* __restrict__ bias,
                              const unsigned long long* __restrict__ pcodes,
                              const float* __restrict__ lutf,
                              const unsigned lim_add,
                              float* __restrict__ out) {
  __shared__ unsigned sredw[4];
  __shared__ float sredf[4];
  __shared__ unsigned long long clist[256];
  __shared__ float sw[256];
  __shared__ int svc[2048];
  __shared__ int scnt;
  __shared__ float sWsum;

  const int tid = threadIdx.x;
  const int b = blockIdx.x;

  const uint4 a0 = *(const uint4*)&cand_d[b * 2048 + tid * 8];
  const uint4 a1 = *(const uint4*)&cand_d[b * 2048 + tid * 8 + 4];
  const uint4 nn = *(const uint4*)&cand_n[b * 2048 + tid * 8];
  unsigned dk[8] = {a0.x, a0.y, a0.z, a0.w, a1.x, a1.y, a1.z, a1.w};
  unsigned ni[8] = {nn.x & 0xFFFFu, nn.x >> 16, nn.y & 0xFFFFu, nn.y >> 16,
                    nn.z & 0xFFFFu, nn.z >> 16, nn.w & 0xFFFFu, nn.w >> 16};

  if (tid == 0) scnt = 0;
  unsigned mn = dk[0];
#pragma unroll
  for (int j = 1; j < 8; j++) mn = (dk[j] < mn) ? dk[j] : mn;
#pragma unroll
  for (int off = 32; off > 0; off >>= 1) {
    const unsigned o = __shfl_xor(mn, off);
    mn = (o < mn) ? o : mn;
  }
  if ((tid & 63) == 0) sredw[tid >> 6] = mn;
  __syncthreads();
  unsigned sMin = sredw[0];
  sMin = (sredw[1] < sMin) ? sredw[1] : sMin;
  sMin = (sredw[2] < sMin) ? sredw[2] : sMin;
  sMin = (sredw[3] < sMin) ? sredw[3] : sMin;
  const unsigned lim = sMin + lim_add;

  const int lane = tid & 63;
  const unsigned long long lm = (1ull << lane) - 1ull;
#pragma unroll
  for (int j = 0; j < 8; j++) {
    const bool pred = dk[j] <= lim;
    const unsigned long long mask = __ballot(pred);
    int base = 0;
    if (lane == 0 && mask) base = atomicAdd(&scnt, __popcll(mask));
    base = __shfl(base, 0);
    if (pred) {
      const int pos = base + __popcll(mask & lm);
      if (pos < 256) clist[pos] = ((unsigned long long)dk[j] << 32) | ni[j];
    }
  }
  __syncthreads();
  const int cnt = min(scnt, 256);

  float dex = 1e30f;
  if (tid < cnt) {
    const int n = (int)(clist[tid] & 0xFFFFFFFFu);
    const unsigned long long c8 = pcodes[n];
    const float* lrow = lutf + b * 2048;
    const unsigned lo = (unsigned)c8, hi = (unsigned)(c8 >> 32);
    dex  = lrow[        (lo       & 255u)];
    dex += lrow[ 256 + ((lo >>  8) & 255u)];
    dex += lrow[ 512 + ((lo >> 16) & 255u)];
    dex += lrow[ 768 + ((lo >> 24)       )];
    dex += lrow[1024 + ( hi        & 255u)];
    dex += lrow[1280 + ((hi >>  8) & 255u)];
    dex += lrow[1536 + ((hi >> 16) & 255u)];
    dex += lrow[1792 + ((hi >> 24)       )];
  }
  for (int i = tid; i < (cnt << 3); i += 256)
    svc[i] = value_codes[((int)(clist[i >> 3] & 0xFFFFFFFFu)) * 8 + (i & 7)];
  float mnf = dex;
#pragma unroll
  for (int off = 32; off > 0; off >>= 1) mnf = fminf(mnf, __shfl_xor(mnf, off));
  if ((tid & 63) == 0) sredf[tid >> 6] = mnf;
  __syncthreads();
  const float dminx = fminf(fminf(sredf[0], sredf[1]), fminf(sredf[2], sredf[3]));
  if (tid < cnt) sw[tid] = __expf(dminx - dex);
  __syncthreads();

  if (tid < 64) {
    float s = 0.f;
    for (int j = tid; j < cnt; j += 64) s += sw[j];
#pragma unroll
    for (int off = 32; off > 0; off >>= 1) s += __shfl_xor(s, off);
    if (tid == 0) sWsum = s;
  }
  __syncthreads();
  const float inv = 1.0f / sWsum;

  const int c0 = tid << 3;
  const int mv = c0 >> 8;
  const int off = c0 & 255;
  float4 acc0 = make_float4(0.f, 0.f, 0.f, 0.f);
  float4 acc1 = make_float4(0.f, 0.f, 0.f, 0.f);
  const float* vbase = vcb + mv * 65536 + off;
  for (int k = 0; k < cnt; k++) {
    const float w = sw[k];
    const float* vp = vbase + svc[(k << 3) + mv] * 256;
    const float4 v0 = *(const float4*)vp;
    const float4 v1 = *(const float4*)(vp + 4);
    acc0.x = fmaf(w, v0.x, acc0.x); acc0.y = fmaf(w, v0.y, acc0.y);
    acc0.z = fmaf(w, v0.z, acc0.z); acc0.w = fmaf(w, v0.w, acc0.w);
    acc1.x = fmaf(w, v1.x, acc1.x); acc1.y = fmaf(w, v1.y, acc1.y);
    acc1.z = fmaf(w, v1.z, acc1.z); acc1.w = fmaf(w, v1.w, acc1.w);
  }
  const float4 b0 = *(const float4*)&bias[c0];
  const float4 b1 = *(const float4*)&bias[c0 + 4];
  *(float4*)&out[b * 2048 + c0] =
      make_float4(fmaf(acc0.x, inv, b0.x), fmaf(acc0.y, inv, b0.y),
                  fmaf(acc0.z, inv, b0.z), fmaf(acc0.w, inv, b0.w));
  *(float4*)&out[b * 2048 + c0 + 4] =
      make_float4(fmaf(acc1.x, inv, b1.x), fmaf(acc1.y, inv, b1.y),
                  fmaf(acc1.z, inv, b1.z), fmaf(acc1.w, inv, b1.w));
}

// ---------------- launch ----------------
extern "C" void kernel_launch(void* const* d_in, const int* in_sizes, int n_in,
                              void* d_out, int out_size, void* d_ws, size_t ws_size,
                              hipStream_t stream) {
  const float* x    = (const float*)d_in[0];
  const float* W    = (const float*)d_in[1];
  const float* kcb  = (const float*)d_in[2];
  const float* vcb  = (const float*)d_in[3];
  const float* bias = (const float*)d_in[4];
  const int* key_codes   = (const int*)d_in[5];
  const int* value_codes = (const int*)d_in[6];
  float* out = (float*)d_out;

  // ws: [0,32MB) fallback cand scratch | q 4MB | lut 8MB | poffs 1MB |
  //     pcodes 0.5MB | i8lut 2MB.
  float* q     = (float*)d_ws + 8388608;
  float* lut   = q + 1048576;
  uint4* poffs = (uint4*)(lut + 2097152);
  unsigned long long* pcodes = (unsigned long long*)(poffs + 65536);
  unsigned* i8lut = (unsigned*)(pcodes + 65536);
  unsigned* cand_d = (unsigned*)d_ws;
  unsigned short* cand_n = (unsigned short*)(cand_d + 2097152);

  hipLaunchKernelGGL(gemm_q_kernel, dim3(16, 16, 2), dim3(512), 0, stream,
                     x, W, key_codes, q, pcodes, poffs);
  hipLaunchKernelGGL(lut_kernel, dim3(4, 16, 8), dim3(256), 0, stream,
                     q, kcb, lut, i8lut);

  const hipError_t attr_rc = hipFuncSetAttribute(
      (const void*)scansel_kernel, hipFuncAttributeMaxDynamicSharedMemorySize, 131072);
  if (attr_rc == hipSuccess) {
    hipLaunchKernelGGL(scansel_kernel, dim3(256), dim3(1024), 131072, stream,
                       lut, i8lut, poffs, pcodes, value_codes, vcb, bias, out);
  } else {
    hipLaunchKernelGGL(scan16_kernel, dim3(1024), dim3(512), 0, stream,
                       lut, pcodes, cand_d, cand_n);
    hipLaunchKernelGGL(select_kernel, dim3(1024), dim3(256), 0, stream,
                       cand_d, cand_n, value_codes, vcb, bias, pcodes, lut,
                       1024u, out);
  }
}

// Round 17
// 165.050 us; speedup vs baseline: 1.0743x; 1.0743x over previous
//
#include <hip/hip_runtime.h>

#define N_ITEMS 65536

// ---------------- Kernel 1: qpart[z] = x @ W (K-chunk 128) + pack plane ------
// z==8 plane (64 blocks) packs key_codes -> pcodes/poffs (overlaps gemm).
__launch_bounds__(256)
__global__ void gemm_q_kernel(const float* __restrict__ A,
                              const float* __restrict__ W,
                              const int* __restrict__ key_codes,
                              float* __restrict__ qpart,
                              unsigned long long* __restrict__ pcodes,
                              uint4* __restrict__ poffs) {
  if (blockIdx.z == 8) {
    const int g0 = (((int)blockIdx.y * 8 + (int)blockIdx.x) * 256 + (int)threadIdx.x) * 4;
#pragma unroll
    for (int t = 0; t < 4; t++) {
      const int gid = g0 + t;
      unsigned long long p = 0ull;
      unsigned h[8];
#pragma unroll
      for (int j = 0; j < 8; j++) {
        const unsigned c = (unsigned)key_codes[gid * 8 + j] & 255u;
        p |= (unsigned long long)c << (8 * j);
        h[j] = c << 6;
      }
      pcodes[gid] = p;
      poffs[gid] = make_uint4(h[0] | (h[1] << 16), h[2] | (h[3] << 16),
                              h[4] | (h[5] << 16), h[6] | (h[7] << 16));
    }
    return;
  }

  __shared__ float As[16][132];
  __shared__ float Bs[16][132];
  const int tid = threadIdx.x;
  const int tx = tid & 15, ty = tid >> 4;
  const int rb = blockIdx.y * 128, cb = blockIdx.x * 128;
  const int kz = blockIdx.z * 128;
  const int ar = tid >> 2, ac = (tid & 3) << 2;
  const int bk = tid >> 5, bc = (tid & 31) << 2;

  float4 va0 = *(const float4*)&A[(rb + ar) * 1024 + kz + ac];
  float4 va1 = *(const float4*)&A[(rb + ar + 64) * 1024 + kz + ac];
  float4 vb0 = *(const float4*)&W[(kz + bk) * 1024 + cb + bc];
  float4 vb1 = *(const float4*)&W[(kz + bk + 8) * 1024 + cb + bc];

  float acc[8][8] = {};
  for (int k0 = 0; k0 < 128; k0 += 16) {
    As[ac + 0][ar] = va0.x; As[ac + 1][ar] = va0.y;
    As[ac + 2][ar] = va0.z; As[ac + 3][ar] = va0.w;
    As[ac + 0][ar + 64] = va1.x; As[ac + 1][ar + 64] = va1.y;
    As[ac + 2][ar + 64] = va1.z; As[ac + 3][ar + 64] = va1.w;
    *(float4*)&Bs[bk][bc] = vb0;
    *(float4*)&Bs[bk + 8][bc] = vb1;
    __syncthreads();
    if (k0 + 16 < 128) {
      va0 = *(const float4*)&A[(rb + ar) * 1024 + kz + k0 + 16 + ac];
      va1 = *(const float4*)&A[(rb + ar + 64) * 1024 + kz + k0 + 16 + ac];
      vb0 = *(const float4*)&W[(kz + k0 + 16 + bk) * 1024 + cb + bc];
      vb1 = *(const float4*)&W[(kz + k0 + 16 + bk + 8) * 1024 + cb + bc];
    }
#pragma unroll
    for (int kk = 0; kk < 16; kk++) {
      const float4 a0 = *(const float4*)&As[kk][ty << 2];
      const float4 a1 = *(const float4*)&As[kk][64 + (ty << 2)];
      const float4 b0 = *(const float4*)&Bs[kk][tx << 2];
      const float4 b1 = *(const float4*)&Bs[kk][64 + (tx << 2)];
      const float ar8[8] = {a0.x, a0.y, a0.z, a0.w, a1.x, a1.y, a1.z, a1.w};
      const float br8[8] = {b0.x, b0.y, b0.z, b0.w, b1.x, b1.y, b1.z, b1.w};
#pragma unroll
      for (int r = 0; r < 8; r++)
#pragma unroll
        for (int c = 0; c < 8; c++)
          acc[r][c] = fmaf(ar8[r], br8[c], acc[r][c]);
    }
    __syncthreads();
  }
  float* outp = qpart + blockIdx.z * 1048576;
#pragma unroll
  for (int rh = 0; rh < 2; rh++)
#pragma unroll
    for (int r = 0; r < 4; r++) {
      const int row = rb + rh * 64 + (ty << 2) + r;
      const int ri = rh * 4 + r;
      *(float4*)&outp[row * 1024 + cb + (tx << 2)] =
          make_float4(acc[ri][0], acc[ri][1], acc[ri][2], acc[ri][3]);
      *(float4*)&outp[row * 1024 + cb + 64 + (tx << 2)] =
          make_float4(acc[ri][4], acc[ri][5], acc[ri][6], acc[ri][7]);
    }
}

// ---------------- Kernel 1b: q = sum_z qpart[z] (pure BW) -------------------
__launch_bounds__(256)
__global__ void qsum_kernel(const float4* __restrict__ qp,
                            float4* __restrict__ q) {
  const int i = blockIdx.x * 256 + threadIdx.x;   // 0..131071
  float4 s0 = qp[i];
  float4 s1 = qp[i + 131072];
#pragma unroll
  for (int z = 1; z < 8; z++) {
    const float4 a = qp[z * 262144 + i];
    const float4 b = qp[z * 262144 + i + 131072];
    s0.x += a.x; s0.y += a.y; s0.z += a.z; s0.w += a.w;
    s1.x += b.x; s1.y += b.y; s1.z += b.z; s1.w += b.w;
  }
  q[i] = s0;
  q[i + 131072] = s1;
}

// ---------------- Kernel 2: lut + DIRECT i8 table emission ------------------
// i8 value = clamp(rint(dt - qa[r] - 96), -127, 127) + 128 -- per-row offset
// preserves per-row ranking exactly; clips covered by lim_add=20 budget.
__launch_bounds__(256)
__global__ void lut_kernel(const float* __restrict__ q,
                           const float* __restrict__ kcb,
                           float* __restrict__ lut,
                           unsigned* __restrict__ i8lut) {
  __shared__ float As[32][68];
  __shared__ float Bs[32][68];
  const int tid = threadIdx.x;
  const int tx = tid & 15, ty = tid >> 4;
  const int m = blockIdx.z;
  const int rb = blockIdx.y * 64;
  const int cb0 = blockIdx.x * 64;
  float acc[4][4] = {};
  float qa[4] = {}, cs[4] = {};
  for (int k0 = 0; k0 < 128; k0 += 32) {
#pragma unroll
    for (int l = 0; l < 2; l++) {
      const int e = tid + l * 256;
      const int row = e >> 3, c4 = (e & 7) << 2;
      const float4 va = *(const float4*)&q[(rb + row) * 1024 + m * 128 + k0 + c4];
      As[c4 + 0][row] = va.x; As[c4 + 1][row] = va.y;
      As[c4 + 2][row] = va.z; As[c4 + 3][row] = va.w;
      const float4 vb = *(const float4*)&kcb[(m * 256 + cb0 + row) * 128 + k0 + c4];
      Bs[c4 + 0][row] = vb.x; Bs[c4 + 1][row] = vb.y;
      Bs[c4 + 2][row] = vb.z; Bs[c4 + 3][row] = vb.w;
    }
    __syncthreads();
#pragma unroll
    for (int kk = 0; kk < 32; kk++) {
      const float4 a = *(const float4*)&As[kk][ty << 2];
      const float4 b = *(const float4*)&Bs[kk][tx << 2];
      const float ar[4] = {a.x, a.y, a.z, a.w};
      const float br[4] = {b.x, b.y, b.z, b.w};
#pragma unroll
      for (int r = 0; r < 4; r++)
#pragma unroll
        for (int c = 0; c < 4; c++)
          acc[r][c] = fmaf(ar[r], br[c], acc[r][c]);
#pragma unroll
      for (int r = 0; r < 4; r++) qa[r] = fmaf(ar[r], ar[r], qa[r]);
#pragma unroll
      for (int c = 0; c < 4; c++) cs[c] = fmaf(br[c], br[c], cs[c]);
    }
    __syncthreads();
  }
  unsigned wpk[4] = {0u, 0u, 0u, 0u};
#pragma unroll
  for (int r = 0; r < 4; r++) {
    const int row = rb + (ty << 2) + r;
    const int col = cb0 + (tx << 2);
    float4 v;
    v.x = qa[r] + cs[0] - 2.0f * acc[r][0];
    v.y = qa[r] + cs[1] - 2.0f * acc[r][1];
    v.z = qa[r] + cs[2] - 2.0f * acc[r][2];
    v.w = qa[r] + cs[3] - 2.0f * acc[r][3];
    *(float4*)&lut[row * 2048 + m * 256 + col] = v;
    const float vb4[4] = {v.x, v.y, v.z, v.w};
#pragma unroll
    for (int c = 0; c < 4; c++) {
      int iv = (int)rintf(vb4[c] - qa[r] - 96.0f);
      iv = max(-127, min(127, iv));
      wpk[c] |= (unsigned)(iv + 128) << (8 * r);
    }
  }
  const int gq = (rb >> 2) + ty;
  const int e0 = m * 256 + cb0 + (tx << 2);
  *(uint4*)&i8lut[gq * 2048 + e0] = make_uint4(wpk[0], wpk[1], wpk[2], wpk[3]);
}

// ---------------- Kernel 3a: FUSED scan+select (best-known 45us config) -----
extern __shared__ char dyn_lds[];

__launch_bounds__(1024)
__global__ void scansel_kernel(const float* __restrict__ lutf,
                               const unsigned* __restrict__ i8lut,
                               const uint4* __restrict__ poffs,
                               const unsigned long long* __restrict__ pcodes,
                               const int* __restrict__ value_codes,
                               const float* __restrict__ vcb,
                               const float* __restrict__ bias,
                               float* __restrict__ out) {
  char* repb = dyn_lds;                               // 131072 B table
  const int tid = threadIdx.x;
  const int g = blockIdx.x;

  // ---- replicate: entry e -> 16 consecutive dwords (e*16+r) ----
  {
    const int lane = tid & 63;
    const uint2 tv = *(const uint2*)&i8lut[g * 2048 + tid * 2];
    const uint4 q0 = make_uint4(tv.x, tv.x, tv.x, tv.x);
    const uint4 q1 = make_uint4(tv.y, tv.y, tv.y, tv.y);
    uint4* repv = (uint4*)dyn_lds;
#pragma unroll
    for (int k = 0; k < 4; k++) {
      const int kk = (k + lane) & 3;
      repv[tid * 8 + kk] = q0;
      repv[tid * 8 + 4 + kk] = q1;
    }
  }
  __syncthreads();

  // ---- scan: 64 items/lane, ping-pong-buffered 8 dword lookups/item ----
  const int r = tid & 15;
  const char* base0 = repb + (r << 2);            // segments 0..3 via imm offs
  const char* base1 = repb + 65536 + (r << 2);    // segments 4..7
  unsigned k0[4], k1[4];
#pragma unroll
  for (int j = 0; j < 4; j++) { k0[j] = 0xFFFFFFFFu; k1[j] = 0xFFFFFFFFu; }

  unsigned A[8], B[8];

  auto issue = [&](unsigned (&BUF)[8], const uint4 cw) {
    BUF[0] = *(const unsigned*)(base0 + (cw.x & 0xFFFFu));
    BUF[1] = *(const unsigned*)(base0 + (cw.x >> 16) + 16384);
    BUF[2] = *(const unsigned*)(base0 + (cw.y & 0xFFFFu) + 32768);
    BUF[3] = *(const unsigned*)(base0 + (cw.y >> 16) + 49152);
    BUF[4] = *(const unsigned*)(base1 + (cw.z & 0xFFFFu));
    BUF[5] = *(const unsigned*)(base1 + (cw.z >> 16) + 16384);
    BUF[6] = *(const unsigned*)(base1 + (cw.w & 0xFFFFu) + 32768);
    BUF[7] = *(const unsigned*)(base1 + (cw.w >> 16) + 49152);
  };

  auto consume = [&](const unsigned (&BUF)[8], const int it) {
    const unsigned M = 0x00FF00FFu;
    unsigned accA = BUF[0] & M;
    unsigned accB = (BUF[0] >> 8) & M;
#pragma unroll
    for (int j = 1; j < 8; j++) {
      accA += BUF[j] & M;
      accB += (BUF[j] >> 8) & M;
    }
    const int ss[4] = {(int)(accA & 0xFFFFu), (int)(accB & 0xFFFFu),
                       (int)(accA >> 16), (int)(accB >> 16)};
#pragma unroll
    for (int j = 0; j < 4; j++) {
      const unsigned key = ((unsigned)ss[j] << 6) | (unsigned)it;
      const unsigned mx = (k0[j] > key) ? k0[j] : key;
      k0[j] = (k0[j] < key) ? k0[j] : key;
      k1[j] = (k1[j] < mx) ? k1[j] : mx;
    }
  };

  issue(A, poffs[tid]);                 // item 0
  uint4 cJ1 = poffs[tid + 1024];        // codes for item it+1
  uint4 cJ2 = poffs[tid + 2048];        // codes for item it+2

  for (int it = 0; it < 64; it += 2) {
    const uint4 cN1 = poffs[tid + (((it + 3) & 63) << 10)];
    const uint4 cN2 = poffs[tid + (((it + 4) & 63) << 10)];
    issue(B, cJ1);
    consume(A, it);
    issue(A, cJ2);
    consume(B, it + 1);
    cJ1 = cN1; cJ2 = cN2;
  }

  // ================= SELECT PHASE (table is dead; overlay LDS) =============
  __syncthreads();   // all table reads complete before overlay writes

  unsigned* cl  = (unsigned*)dyn_lds;                       // [4][256] (d<<16)|n
  float* wts    = (float*)(dyn_lds + 4096);                 // [4][256]
  unsigned long long* sv8 = (unsigned long long*)(dyn_lds + 8192); // [4][256]
  float* gred   = (float*)(dyn_lds + 16384);                // [4][4] scratch
  unsigned* rmin = (unsigned*)(dyn_lds + 16448);            // [4]
  int* rcnt     = (int*)(dyn_lds + 16464);                  // [4]
  float* rws    = (float*)(dyn_lds + 16480);                // [4] 1/wsum

  if (tid < 4) { rmin[tid] = 0xFFFFFFFFu; rcnt[tid] = 0; }
  __syncthreads();

  // per-row quantized min
#pragma unroll
  for (int j = 0; j < 4; j++) {
    unsigned d = k0[j] >> 6;
#pragma unroll
    for (int off = 32; off > 0; off >>= 1) {
      const unsigned o = __shfl_xor(d, off);
      d = (o < d) ? o : d;
    }
    if ((tid & 63) == 0) atomicMin(&rmin[j], d);
  }
  __syncthreads();

  // ballot-compact candidates within window
  {
    const int lane = tid & 63;
    const unsigned long long lm = (1ull << lane) - 1ull;
#pragma unroll
    for (int j = 0; j < 4; j++) {
      const unsigned lim = rmin[j] + 20u;
#pragma unroll
      for (int c = 0; c < 2; c++) {
        const unsigned key = c ? k1[j] : k0[j];
        const unsigned d = key >> 6;
        const bool pred = d <= lim;
        const unsigned long long m = __ballot(pred);
        int base = 0;
        if (lane == 0 && m) base = atomicAdd(&rcnt[j], __popcll(m));
        base = __shfl(base, 0);
        if (pred) {
          const int pos = base + __popcll(m & lm);
          if (pos < 256)
            cl[j * 256 + pos] = (d << 16) | ((key & 63u) << 10) | (unsigned)tid;
        }
      }
    }
  }
  __syncthreads();

  // exact fp32 re-score (group j = tid>>8 handles row j)
  const int gj = tid >> 8, gt = tid & 255;
  const int cnt_g = min(rcnt[gj], 256);
  float dex = 1e30f;
  if (gt < cnt_g) {
    const unsigned pc = cl[gj * 256 + gt];
    const int n = (int)(pc & 0xFFFFu);
    const unsigned long long c8 = pcodes[n];
    const uint4 vc0 = *(const uint4*)&value_codes[n * 8];
    const uint4 vc1 = *(const uint4*)&value_codes[n * 8 + 4];
    sv8[gj * 256 + gt] =
        (unsigned long long)(vc0.x & 255u)        | ((unsigned long long)(vc0.y & 255u) << 8)  |
        ((unsigned long long)(vc0.z & 255u) << 16) | ((unsigned long long)(vc0.w & 255u) << 24) |
        ((unsigned long long)(vc1.x & 255u) << 32) | ((unsigned long long)(vc1.y & 255u) << 40) |
        ((unsigned long long)(vc1.z & 255u) << 48) | ((unsigned long long)(vc1.w & 255u) << 56);
    const float* lrow = lutf + ((g << 2) + gj) * 2048;
    const unsigned lo = (unsigned)c8, hi = (unsigned)(c8 >> 32);
    dex  = lrow[        (lo       & 255u)];
    dex += lrow[ 256 + ((lo >>  8) & 255u)];
    dex += lrow[ 512 + ((lo >> 16) & 255u)];
    dex += lrow[ 768 + ((lo >> 24)       )];
    dex += lrow[1024 + ( hi        & 255u)];
    dex += lrow[1280 + ((hi >>  8) & 255u)];
    dex += lrow[1536 + ((hi >> 16) & 255u)];
    dex += lrow[1792 + ((hi >> 24)       )];
  }
  // group min of dex (4 waves per group)
  float mnf = dex;
#pragma unroll
  for (int off = 32; off > 0; off >>= 1) mnf = fminf(mnf, __shfl_xor(mnf, off));
  if ((tid & 63) == 0) gred[gj * 4 + ((tid >> 6) & 3)] = mnf;
  __syncthreads();
  const float dminx = fminf(fminf(gred[gj * 4], gred[gj * 4 + 1]),
                            fminf(gred[gj * 4 + 2], gred[gj * 4 + 3]));
  const float w = (gt < cnt_g) ? __expf(dminx - dex) : 0.f;
  wts[gj * 256 + gt] = w;
  // group sum of w
  float sw_ = w;
#pragma unroll
  for (int off = 32; off > 0; off >>= 1) sw_ += __shfl_xor(sw_, off);
  __syncthreads();   // gred min-reads done; safe to overwrite
  if ((tid & 63) == 0) gred[gj * 4 + ((tid >> 6) & 3)] = sw_;
  __syncthreads();
  if (gt == 0)
    rws[gj] = 1.0f / (gred[gj * 4] + gred[gj * 4 + 1] + gred[gj * 4 + 2] + gred[gj * 4 + 3]);
  __syncthreads();

  // value gather + output: rows in pairs (h = tid>>9 selects row of pair)
  const int h = tid >> 9, u = tid & 511;
  const int col = u << 2;
  const int mv = col >> 8;
  const int co = col & 255;
  const float* vb2 = vcb + mv * 65536 + co;
  const float4 bb = *(const float4*)&bias[col];
#pragma unroll
  for (int jr = 0; jr < 2; jr++) {
    const int j = (jr << 1) | h;
    const int row = (g << 2) + j;
    const int cj = min(rcnt[j], 256);
    float4 acc = make_float4(0.f, 0.f, 0.f, 0.f);
    int k = 0;
    for (; k + 1 < cj; k += 2) {
      const float w0 = wts[j * 256 + k];
      const float w1 = wts[j * 256 + k + 1];
      const unsigned c0 = (unsigned)((sv8[j * 256 + k] >> (mv * 8)) & 255ull);
      const unsigned c1 = (unsigned)((sv8[j * 256 + k + 1] >> (mv * 8)) & 255ull);
      const float4 v0 = *(const float4*)(vb2 + c0 * 256);
      const float4 v1 = *(const float4*)(vb2 + c1 * 256);
      acc.x = fmaf(w0, v0.x, acc.x); acc.y = fmaf(w0, v0.y, acc.y);
      acc.z = fmaf(w0, v0.z, acc.z); acc.w = fmaf(w0, v0.w, acc.w);
      acc.x = fmaf(w1, v1.x, acc.x); acc.y = fmaf(w1, v1.y, acc.y);
      acc.z = fmaf(w1, v1.z, acc.z); acc.w = fmaf(w1, v1.w, acc.w);
    }
    if (k < cj) {
      const float w0 = wts[j * 256 + k];
      const unsigned c0 = (unsigned)((sv8[j * 256 + k] >> (mv * 8)) & 255ull);
      const float4 v0 = *(const float4*)(vb2 + c0 * 256);
      acc.x = fmaf(w0, v0.x, acc.x); acc.y = fmaf(w0, v0.y, acc.y);
      acc.z = fmaf(w0, v0.z, acc.z); acc.w = fmaf(w0, v0.w, acc.w);
    }
    const float iv = rws[j];
    *(float4*)&out[row * 2048 + col] =
        make_float4(fmaf(acc.x, iv, bb.x), fmaf(acc.y, iv, bb.y),
                    fmaf(acc.z, iv, bb.z), fmaf(acc.w, iv, bb.w));
  }
}

// ---------------- Kernel 3b: fallback 64KB scan (verified) ----------------
__launch_bounds__(512)
__global__ void scan16_kernel(const float* __restrict__ lut,
                              const unsigned long long* __restrict__ pcodes,
                              unsigned* __restrict__ cand_d,
                              unsigned short* __restrict__ cand_n) {
  __shared__ short sRep[32768];
  const int tid = threadIdx.x;
  const int b = blockIdx.x;

  const float4 v4 = *(const float4*)&lut[b * 2048 + tid * 4];
  float s4 = v4.x + v4.y + v4.z + v4.w;
#pragma unroll
  for (int off = 32; off > 0; off >>= 1) s4 += __shfl_xor(s4, off);
  const float mean = s4 * (1.0f / 256.0f);

  const float vals[4] = {v4.x, v4.y, v4.z, v4.w};
#pragma unroll
  for (int k2 = 0; k2 < 4; k2++) {
    float f = (vals[k2] - mean) * 64.0f;
    f = fmaxf(fminf(f, 32000.0f), -32000.0f);
    const int iv = (int)rintf(f);
    const unsigned hw = (unsigned)(unsigned short)iv;
    const unsigned wrd = hw | (hw << 16);
    const uint4 wv = make_uint4(wrd, wrd, wrd, wrd);
    const int e = tid * 4 + k2;
    *(uint4*)&((unsigned*)sRep)[e * 8] = wv;
    *(uint4*)&((unsigned*)sRep)[e * 8 + 4] = wv;
  }
  __syncthreads();

  const int r = tid & 15;
  int d0 = 0x7FFFFFFF, d1 = 0x7FFFFFFF, d2 = 0x7FFFFFFF, d3 = 0x7FFFFFFF;
  int i0 = 0, i1 = 0, i2 = 0, i3 = 0;

  unsigned long long c8 = pcodes[tid];
  for (int it = 0; it < 128; it++) {
    const int n = tid + (it << 9);
    unsigned long long nxt = 0ull;
    if (it < 127) nxt = pcodes[n + 512];
    const unsigned lo = (unsigned)c8;
    const unsigned hi = (unsigned)(c8 >> 32);
    int s;
    s  = sRep[(((lo      ) & 255u) << 4) + r        ];
    s += sRep[(((lo >>  8) & 255u) << 4) + r +  4096];
    s += sRep[(((lo >> 16) & 255u) << 4) + r +  8192];
    s += sRep[(((lo >> 24)       ) << 4) + r + 12288];
    s += sRep[(((hi      ) & 255u) << 4) + r + 16384];
    s += sRep[(((hi >>  8) & 255u) << 4) + r + 20480];
    s += sRep[(((hi >> 16) & 255u) << 4) + r + 24576];
    s += sRep[(((hi >> 24)       ) << 4) + r + 28672];
    if (s < d3) {
      if (s < d1) {
        if (s < d0) { d3 = d2; i3 = i2; d2 = d1; i2 = i1; d1 = d0; i1 = i0; d0 = s; i0 = n; }
        else        { d3 = d2; i3 = i2; d2 = d1; i2 = i1; d1 = s; i1 = n; }
      } else {
        if (s < d2) { d3 = d2; i3 = i2; d2 = s; i2 = n; }
        else        { d3 = s; i3 = n; }
      }
    }
    c8 = nxt;
  }

  const int base = b * 2048 + tid * 4;
  const uint4 dv = make_uint4((unsigned)(d0 + 0x40000000), (unsigned)(d1 + 0x40000000),
                              (unsigned)(d2 + 0x40000000), (unsigned)(d3 + 0x40000000));
  *(uint4*)&cand_d[base] = dv;
  const unsigned ni01 = (unsigned)i0 | ((unsigned)i1 << 16);
  const unsigned ni23 = (unsigned)i2 | ((unsigned)i3 << 16);
  *(uint2*)&cand_n[base] = make_uint2(ni01, ni23);
}

// ---------------- Kernel 4 (fallback path only): select + re-score ----------
__launch_bounds__(256)
__global__ void select_kernel(const unsigned* __restrict__ cand_d,
                              const unsigned short* __restrict__ cand_n,
                              const int* __restrict__ value_codes,
                              const float* __restrict__ vcb,
                              const float* __restrict__ bias,
                              const unsigned long long* __restrict__ pcodes,
                              const float* __restrict__ lutf,
                              const unsigned lim_add,
                              float* __restrict__ out) {
  __shared__ unsigned sredw[4];
  __shared__ float sredf[4];
  __shared__ unsigned long long clist[256];
  __shared__ float sw[256];
  __shared__ int svc[2048];
  __shared__ int scnt;
  __shared__ float sWsum;

  const int tid = threadIdx.x;
  const int b = blockIdx.x;

  const uint4 a0 = *(const uint4*)&cand_d[b * 2048 + tid * 8];
  const uint4 a1 = *(const uint4*)&cand_d[b * 2048 + tid * 8 + 4];
  const uint4 nn = *(const uint4*)&cand_n[b * 2048 + tid * 8];
  unsigned dk[8] = {a0.x, a0.y, a0.z, a0.w, a1.x, a1.y, a1.z, a1.w};
  unsigned ni[8] = {nn.x & 0xFFFFu, nn.x >> 16, nn.y & 0xFFFFu, nn.y >> 16,
                    nn.z & 0xFFFFu, nn.z >> 16, nn.w & 0xFFFFu, nn.w >> 16};

  if (tid == 0) scnt = 0;
  unsigned mn = dk[0];
#pragma unroll
  for (int j = 1; j < 8; j++) mn = (dk[j] < mn) ? dk[j] : mn;
#pragma unroll
  for (int off = 32; off > 0; off >>= 1) {
    const unsigned o = __shfl_xor(mn, off);
    mn = (o < mn) ? o : mn;
  }
  if ((tid & 63) == 0) sredw[tid >> 6] = mn;
  __syncthreads();
  unsigned sMin = sredw[0];
  sMin = (sredw[1] < sMin) ? sredw[1] : sMin;
  sMin = (sredw[2] < sMin) ? sredw[2] : sMin;
  sMin = (sredw[3] < sMin) ? sredw[3] : sMin;
  const unsigned lim = sMin + lim_add;

  const int lane = tid & 63;
  const unsigned long long lm = (1ull << lane) - 1ull;
#pragma unroll
  for (int j = 0; j < 8; j++) {
    const bool pred = dk[j] <= lim;
    const unsigned long long mask = __ballot(pred);
    int base = 0;
    if (lane == 0 && mask) base = atomicAdd(&scnt, __popcll(mask));
    base = __shfl(base, 0);
    if (pred) {
      const int pos = base + __popcll(mask & lm);
      if (pos < 256) clist[pos] = ((unsigned long long)dk[j] << 32) | ni[j];
    }
  }
  __syncthreads();
  const int cnt = min(scnt, 256);

  float dex = 1e30f;
  if (tid < cnt) {
    const int n = (int)(clist[tid] & 0xFFFFFFFFu);
    const unsigned long long c8 = pcodes[n];
    const float* lrow = lutf + b * 2048;
    const unsigned lo = (unsigned)c8, hi = (unsigned)(c8 >> 32);
    dex  = lrow[        (lo       & 255u)];
    dex += lrow[ 256 + ((lo >>  8) & 255u)];
    dex += lrow[ 512 + ((lo >> 16) & 255u)];
    dex += lrow[ 768 + ((lo >> 24)       )];
    dex += lrow[1024 + ( hi        & 255u)];
    dex += lrow[1280 + ((hi >>  8) & 255u)];
    dex += lrow[1536 + ((hi >> 16) & 255u)];
    dex += lrow[1792 + ((hi >> 24)       )];
  }
  for (int i = tid; i < (cnt << 3); i += 256)
    svc[i] = value_codes[((int)(clist[i >> 3] & 0xFFFFFFFFu)) * 8 + (i & 7)];
  float mnf = dex;
#pragma unroll
  for (int off = 32; off > 0; off >>= 1) mnf = fminf(mnf, __shfl_xor(mnf, off));
  if ((tid & 63) == 0) sredf[tid >> 6] = mnf;
  __syncthreads();
  const float dminx = fminf(fminf(sredf[0], sredf[1]), fminf(sredf[2], sredf[3]));
  if (tid < cnt) sw[tid] = __expf(dminx - dex);
  __syncthreads();

  if (tid < 64) {
    float s = 0.f;
    for (int j = tid; j < cnt; j += 64) s += sw[j];
#pragma unroll
    for (int off = 32; off > 0; off >>= 1) s += __shfl_xor(s, off);
    if (tid == 0) sWsum = s;
  }
  __syncthreads();
  const float inv = 1.0f / sWsum;

  const int c0 = tid << 3;
  const int mv = c0 >> 8;
  const int off = c0 & 255;
  float4 acc0 = make_float4(0.f, 0.f, 0.f, 0.f);
  float4 acc1 = make_float4(0.f, 0.f, 0.f, 0.f);
  const float* vbase = vcb + mv * 65536 + off;
  for (int k = 0; k < cnt; k++) {
    const float w = sw[k];
    const float* vp = vbase + svc[(k << 3) + mv] * 256;
    const float4 v0 = *(const float4*)vp;
    const float4 v1 = *(const float4*)(vp + 4);
    acc0.x = fmaf(w, v0.x, acc0.x); acc0.y = fmaf(w, v0.y, acc0.y);
    acc0.z = fmaf(w, v0.z, acc0.z); acc0.w = fmaf(w, v0.w, acc0.w);
    acc1.x = fmaf(w, v1.x, acc1.x); acc1.y = fmaf(w, v1.y, acc1.y);
    acc1.z = fmaf(w, v1.z, acc1.z); acc1.w = fmaf(w, v1.w, acc1.w);
  }
  const float4 b0 = *(const float4*)&bias[c0];
  const float4 b1 = *(const float4*)&bias[c0 + 4];
  *(float4*)&out[b * 2048 + c0] =
      make_float4(fmaf(acc0.x, inv, b0.x), fmaf(acc0.y, inv, b0.y),
                  fmaf(acc0.z, inv, b0.z), fmaf(acc0.w, inv, b0.w));
  *(float4*)&out[b * 2048 + c0 + 4] =
      make_float4(fmaf(acc1.x, inv, b1.x), fmaf(acc1.y, inv, b1.y),
                  fmaf(acc1.z, inv, b1.z), fmaf(acc1.w, inv, b1.w));
}

// ---------------- launch ----------------
extern "C" void kernel_launch(void* const* d_in, const int* in_sizes, int n_in,
                              void* d_out, int out_size, void* d_ws, size_t ws_size,
                              hipStream_t stream) {
  const float* x    = (const float*)d_in[0];
  const float* W    = (const float*)d_in[1];
  const float* kcb  = (const float*)d_in[2];
  const float* vcb  = (const float*)d_in[3];
  const float* bias = (const float*)d_in[4];
  const int* key_codes   = (const int*)d_in[5];
  const int* value_codes = (const int*)d_in[6];
  float* out = (float*)d_out;

  // ws: qpart 32MB | q 4MB | lut 8MB | poffs 1MB | pcodes 0.5MB | i8lut 2MB.
  // cand buffers (fallback only) alias qpart. lut live through scansel.
  float* qpart = (float*)d_ws;
  float* q     = qpart + 8388608;
  float* lut   = q + 1048576;
  uint4* poffs = (uint4*)(lut + 2097152);
  unsigned long long* pcodes = (unsigned long long*)(poffs + 65536);
  unsigned* i8lut = (unsigned*)(pcodes + 65536);
  unsigned* cand_d = (unsigned*)d_ws;
  unsigned short* cand_n = (unsigned short*)(cand_d + 2097152);

  hipLaunchKernelGGL(gemm_q_kernel, dim3(8, 8, 9), dim3(256), 0, stream,
                     x, W, key_codes, qpart, pcodes, poffs);
  hipLaunchKernelGGL(qsum_kernel, dim3(512), dim3(256), 0, stream,
                     (const float4*)qpart, (float4*)q);
  hipLaunchKernelGGL(lut_kernel, dim3(4, 16, 8), dim3(256), 0, stream,
                     q, kcb, lut, i8lut);

  const hipError_t attr_rc = hipFuncSetAttribute(
      (const void*)scansel_kernel, hipFuncAttributeMaxDynamicSharedMemorySize, 131072);
  if (attr_rc == hipSuccess) {
    hipLaunchKernelGGL(scansel_kernel, dim3(256), dim3(1024), 131072, stream,
                       lut, i8lut, poffs, pcodes, value_codes, vcb, bias, out);
  } else {
    hipLaunchKernelGGL(scan16_kernel, dim3(1024), dim3(512), 0, stream,
                       lut, pcodes, cand_d, cand_n);
    hipLaunchKernelGGL(select_kernel, dim3(1024), dim3(256), 0, stream,
                       cand_d, cand_n, value_codes, vcb, bias, pcodes, lut,
                       1024u, out);
  }
}